// Round 12
// baseline (384.445 us; speedup 1.0000x reference)
//
#include <hip/hip_runtime.h>

#define B_ 16
#define N_ 2048
#define IN_ 12
#define H_ 64
#define K_ 16

// Skewed LDS index: row-major [r][k] tiles, stride 68 + 4-float skew per 4 rows.
#define IDX(r, k) ((r) * 68 + ((r) >> 2) * 4 + (k))

// ---------------------------------------------------------------------------
// Kernel A: emb = relu(x@W1+b1)@W2+b2 (one wave per row); sref = 1/max(||e||,eps)
// (byte-identical to round 4 — passing arithmetic, do not modify)
// ---------------------------------------------------------------------------
__global__ __launch_bounds__(256) void emb_kernel(
    const float* __restrict__ x, const float* __restrict__ W1,
    const float* __restrict__ b1, const float* __restrict__ W2,
    const float* __restrict__ b2, float* __restrict__ emb_out,
    float* __restrict__ sref) {
  const int lane = threadIdx.x & 63;
  const int wid = threadIdx.x >> 6;
  const long long row = (long long)blockIdx.x * 4 + wid;  // 0..32767

  const float* xr = x + row * IN_;
  float xv[IN_];
#pragma unroll
  for (int k = 0; k < IN_; ++k) xv[k] = xr[k];

  float acc = b1[lane];
#pragma unroll
  for (int k = 0; k < IN_; ++k) acc += xv[k] * W1[k * H_ + lane];
  float h = fmaxf(acc, 0.f);

  float e = b2[lane];
#pragma unroll
  for (int j = 0; j < H_; ++j) {
    float hj = __shfl(h, j, 64);
    e += hj * W2[j * H_ + lane];
  }

  float ss = e * e;
#pragma unroll
  for (int off = 32; off; off >>= 1) ss += __shfl_xor(ss, off, 64);
  float s = 1.0f / fmaxf(sqrtf(ss), 1e-12f);

  emb_out[row * H_ + lane] = e;
  if (lane == 0) sref[row] = s;
}

// ---------------------------------------------------------------------------
// Kernel B: sim tile GEMM, 128x64 per block, 8x4 outputs/thread.
// Arithmetic expression-identical to round 6 (passing): A staged in LDS as
// fl(e*s_i); B read RAW. NEW: B comes straight from global (same addresses,
// same bits as the old LDS copy) — B-tile is 16 KB, L1-resident, 4-lane
// shared. Removes the B staging phase + its barrier coupling; B loads
// pipeline under the FMA loop via vmcnt.
// ---------------------------------------------------------------------------
__global__ __launch_bounds__(256) void sim_kernel(
    const float* __restrict__ emb, const float* __restrict__ sref,
    float* __restrict__ adj) {
  __shared__ float As[8824];  // IDX(127,63)+1  (~35 KB)

  const int t = threadIdx.x;
  const int nTj = N_ / 64;                 // 32
  const int tilesPerB = (N_ / 128) * nTj;  // 512
  const int b = blockIdx.x / tilesPerB;
  const int tl = blockIdx.x % tilesPerB;
  const int ti = tl / nTj, tj = tl % nTj;

  const float* Eb = emb + (size_t)b * N_ * H_;
  const float* srb = sref + b * N_;

  // ---- stage A-tile: rows ti*128..+128, pre-scaled by s_i ----
  {
    const int r = t >> 1;              // 0..127
    const int k0 = (t & 1) * 32;       // 0 or 32
    const float sA = srb[ti * 128 + r];
    const float* src = Eb + (size_t)(ti * 128 + r) * H_ + k0;
#pragma unroll
    for (int i = 0; i < 8; ++i) {
      const float4 v = *(const float4*)(src + i * 4);
      float4 w;
      w.x = v.x * sA; w.y = v.y * sA; w.z = v.z * sA; w.w = v.w * sA;
      *(float4*)&As[IDX(r, k0 + i * 4)] = w;
    }
  }
  __syncthreads();

  const int tx = t & 15, ty = t >> 4;
  const int r0 = ty * 8, c0 = tx * 4;

  float4 acc[8][4];
#pragma unroll
  for (int rr = 0; rr < 8; ++rr)
#pragma unroll
    for (int cc = 0; cc < 4; ++cc) acc[rr][cc] = make_float4(0.f, 0.f, 0.f, 0.f);

  int aoff[8];
#pragma unroll
  for (int rr = 0; rr < 8; ++rr) aoff[rr] = IDX(r0 + rr, 0);
  const float* bp0 = Eb + (size_t)(tj * 64 + c0 + 0) * H_;
  const float* bp1 = Eb + (size_t)(tj * 64 + c0 + 1) * H_;
  const float* bp2 = Eb + (size_t)(tj * 64 + c0 + 2) * H_;
  const float* bp3 = Eb + (size_t)(tj * 64 + c0 + 3) * H_;

#pragma unroll 4
  for (int dg = 0; dg < 16; ++dg) {
    float4 av[8], bv[4];
    bv[0] = *(const float4*)(bp0 + dg * 4);
    bv[1] = *(const float4*)(bp1 + dg * 4);
    bv[2] = *(const float4*)(bp2 + dg * 4);
    bv[3] = *(const float4*)(bp3 + dg * 4);
#pragma unroll
    for (int rr = 0; rr < 8; ++rr) av[rr] = *(const float4*)&As[aoff[rr] + dg * 4];
#pragma unroll
    for (int rr = 0; rr < 8; ++rr)
#pragma unroll
      for (int cc = 0; cc < 4; ++cc) {
        acc[rr][cc].x += av[rr].x * bv[cc].x;
        acc[rr][cc].y += av[rr].y * bv[cc].y;
        acc[rr][cc].z += av[rr].z * bv[cc].z;
        acc[rr][cc].w += av[rr].w * bv[cc].w;
      }
  }

  // ---- epilogue: (x+y+z+w) * s_j, store ----
  const float4 sjv = *(const float4*)(srb + tj * 64 + c0);
  float* out = adj + (size_t)b * N_ * N_ + (size_t)(ti * 128 + r0) * N_ + tj * 64 + c0;
#pragma unroll
  for (int rr = 0; rr < 8; ++rr) {
    float4 o;
    o.x = (acc[rr][0].x + acc[rr][0].y + acc[rr][0].z + acc[rr][0].w) * sjv.x;
    o.y = (acc[rr][1].x + acc[rr][1].y + acc[rr][1].z + acc[rr][1].w) * sjv.y;
    o.z = (acc[rr][2].x + acc[rr][2].y + acc[rr][2].z + acc[rr][2].w) * sjv.z;
    o.w = (acc[rr][3].x + acc[rr][3].y + acc[rr][3].z + acc[rr][3].w) * sjv.w;
    *(float4*)(out + (size_t)rr * N_) = o;
  }
}

// ---------------------------------------------------------------------------
// Kernel C: in-place top-16 per row. (byte-identical to round 11 — passing)
// u64 key = mono(v)<<32 | (N-1-j); per-lane top-2 cache; 32-bit value
// butterfly + unique-max broadcast; exact u64 fallback on value ties.
// ---------------------------------------------------------------------------
__device__ __forceinline__ unsigned mono32(float v) {
  unsigned u = __float_as_uint(v);
  return u ^ ((unsigned)((int)u >> 31) | 0x80000000u);
}

__global__ __launch_bounds__(256) void topk_kernel(float* __restrict__ adj) {
  const int lane = threadIdx.x & 63;
  const int wid = threadIdx.x >> 6;
  const size_t row = (size_t)blockIdx.x * 4 + wid;  // 0..32767
  float* rp = adj + row * N_;

  // element j = (s>>2)*256 + lane*4 + (s&3) lives in vals[s]
  float vals[32];
#pragma unroll
  for (int g = 0; g < 8; ++g) {
    const float4 v = *((const float4*)rp + g * 64 + lane);
    vals[g * 4 + 0] = v.x; vals[g * 4 + 1] = v.y;
    vals[g * 4 + 2] = v.z; vals[g * 4 + 3] = v.w;
  }

  // ---- per-lane top-2 (ascending slot scan, strict > => lowest j on ties)
  float v1 = vals[0], v2 = -2.f;
  int s1 = 0, sB = 0;
#pragma unroll
  for (int s = 1; s < 32; ++s) {
    const float v = vals[s];
    if (v > v1) { v2 = v1; sB = s1; v1 = v; s1 = s; }
    else if (v > v2) { v2 = v; sB = s; }
  }
#define SLOT2J(S) ((((S) >> 2) << 8) + (lane << 2) + ((S)&3))
  unsigned long long lk =
      ((unsigned long long)mono32(v1) << 32) | (unsigned)(N_ - 1 - SLOT2J(s1));
  unsigned long long k2 =
      ((unsigned long long)mono32(v2) << 32) | (unsigned)(N_ - 1 - SLOT2J(sB));

  unsigned taken = 0u;
  int nlost = 0;

  for (int it = 0; it < K_; ++it) {
    const unsigned lv = (unsigned)(lk >> 32);
    unsigned bv = lv;
#pragma unroll
    for (int off = 32; off; off >>= 1) {
      const unsigned ov = __shfl_xor(bv, off, 64);
      if (ov > bv) bv = ov;
    }
    const unsigned long long mask = __ballot(lv == bv);
    unsigned long long bk;
    if (__popcll(mask) == 1) {
      const int srcl = (int)(__ffsll((long long)mask) - 1);
      bk = __shfl(lk, srcl, 64);
    } else {
      bk = lk;  // cross-lane value tie (rare, wave-uniform): exact u64
#pragma unroll
      for (int off = 32; off; off >>= 1) {
        const unsigned long long ok = __shfl_xor(bk, off, 64);
        if (ok > bk) bk = ok;
      }
    }

    const int j = N_ - 1 - (int)(bk & 0xFFFFFFFFull);
    const bool own = ((j >> 2) & 63) == lane;
    if (own) {
      taken |= 1u << (((j >> 8) << 2) | (j & 3));
      if (it < K_ - 1) {
        if (nlost == 0) {
          lk = k2;        // promote cached #2
          nlost = 1;
        } else {
          nlost = 2;      // mark: rescan below
        }
      }
    }
    if (own && nlost == 2) {
      float nv = -2.f; int ns = 0;
#pragma unroll
      for (int s = 0; s < 32; ++s) {
        if (!((taken >> s) & 1u) && vals[s] > nv) { nv = vals[s]; ns = s; }
      }
      lk = ((unsigned long long)mono32(nv) << 32) |
           (unsigned)(N_ - 1 - SLOT2J(ns));
    }
  }

  // merged write: winners keep value, everything else zero
#pragma unroll
  for (int g = 0; g < 8; ++g) {
    float4 o;
    o.x = ((taken >> (g * 4 + 0)) & 1u) ? vals[g * 4 + 0] : 0.f;
    o.y = ((taken >> (g * 4 + 1)) & 1u) ? vals[g * 4 + 1] : 0.f;
    o.z = ((taken >> (g * 4 + 2)) & 1u) ? vals[g * 4 + 2] : 0.f;
    o.w = ((taken >> (g * 4 + 3)) & 1u) ? vals[g * 4 + 3] : 0.f;
    *((float4*)rp + g * 64 + lane) = o;
  }
}

extern "C" void kernel_launch(void* const* d_in, const int* in_sizes, int n_in,
                              void* d_out, int out_size, void* d_ws, size_t ws_size,
                              hipStream_t stream) {
  const float* x  = (const float*)d_in[0];
  const float* W1 = (const float*)d_in[1];
  const float* b1 = (const float*)d_in[2];
  const float* W2 = (const float*)d_in[3];
  const float* b2 = (const float*)d_in[4];

  float* adj  = (float*)d_out;                              // B*N*N
  float* embo = (float*)d_out + (size_t)B_ * N_ * N_;       // B*N*H
  float* sref = (float*)d_ws;                               // B*N floats

  emb_kernel<<<(B_ * N_) / 4, 256, 0, stream>>>(x, W1, b1, W2, b2, embo, sref);
  sim_kernel<<<B_ * (N_ / 128) * (N_ / 64), 256, 0, stream>>>(embo, sref, adj);
  topk_kernel<<<(B_ * N_) / 4, 256, 0, stream>>>(adj);
}

// Round 13
// 242.377 us; speedup vs baseline: 1.5861x; 1.5861x over previous
//
#include <hip/hip_runtime.h>

#define B_ 16
#define N_ 2048
#define IN_ 12
#define H_ 64
#define K_ 16

// Skewed LDS index: row-major [r][k] tiles, stride 68 + 4-float skew per 4 rows.
#define IDX(r, k) ((r) * 68 + ((r) >> 2) * 4 + (k))

// ---------------------------------------------------------------------------
// Kernel A: emb = relu(x@W1+b1)@W2+b2 (one wave per row); sref = 1/max(||e||,eps)
// (byte-identical to round 4 — passing arithmetic, do not modify)
// ---------------------------------------------------------------------------
__global__ __launch_bounds__(256) void emb_kernel(
    const float* __restrict__ x, const float* __restrict__ W1,
    const float* __restrict__ b1, const float* __restrict__ W2,
    const float* __restrict__ b2, float* __restrict__ emb_out,
    float* __restrict__ sref) {
  const int lane = threadIdx.x & 63;
  const int wid = threadIdx.x >> 6;
  const long long row = (long long)blockIdx.x * 4 + wid;  // 0..32767

  const float* xr = x + row * IN_;
  float xv[IN_];
#pragma unroll
  for (int k = 0; k < IN_; ++k) xv[k] = xr[k];

  float acc = b1[lane];
#pragma unroll
  for (int k = 0; k < IN_; ++k) acc += xv[k] * W1[k * H_ + lane];
  float h = fmaxf(acc, 0.f);

  float e = b2[lane];
#pragma unroll
  for (int j = 0; j < H_; ++j) {
    float hj = __shfl(h, j, 64);
    e += hj * W2[j * H_ + lane];
  }

  float ss = e * e;
#pragma unroll
  for (int off = 32; off; off >>= 1) ss += __shfl_xor(ss, off, 64);
  float s = 1.0f / fmaxf(sqrtf(ss), 1e-12f);

  emb_out[row * H_ + lane] = e;
  if (lane == 0) sref[row] = s;
}

// ---------------------------------------------------------------------------
// Kernel B: sim tile GEMM, 128x64 per block, 8x4 outputs/thread.
// (byte-identical to round 6 — best measured across 5 variants, do not modify)
// ---------------------------------------------------------------------------
__global__ __launch_bounds__(256) void sim_kernel(
    const float* __restrict__ emb, const float* __restrict__ sref,
    float* __restrict__ adj) {
  __shared__ float As[8824];  // IDX(127,63)+1
  __shared__ float Bs[4408];  // IDX(63,63)+1

  const int t = threadIdx.x;
  const int nTj = N_ / 64;                 // 32
  const int tilesPerB = (N_ / 128) * nTj;  // 512
  const int b = blockIdx.x / tilesPerB;
  const int tl = blockIdx.x % tilesPerB;
  const int ti = tl / nTj, tj = tl % nTj;

  const float* Eb = emb + (size_t)b * N_ * H_;
  const float* srb = sref + b * N_;

  // ---- stage A-tile: rows ti*128..+128, pre-scaled by s_i ----
  {
    const int r = t >> 1;              // 0..127
    const int k0 = (t & 1) * 32;       // 0 or 32
    const float sA = srb[ti * 128 + r];
    const float* src = Eb + (size_t)(ti * 128 + r) * H_ + k0;
#pragma unroll
    for (int i = 0; i < 8; ++i) {
      const float4 v = *(const float4*)(src + i * 4);
      float4 w;
      w.x = v.x * sA; w.y = v.y * sA; w.z = v.z * sA; w.w = v.w * sA;
      *(float4*)&As[IDX(r, k0 + i * 4)] = w;
    }
  }
  // ---- stage B-tile: rows tj*64..+64, raw e_j ----
  {
    const int r = t >> 2;              // 0..63
    const int k0 = (t & 3) * 16;
    const float* src = Eb + (size_t)(tj * 64 + r) * H_ + k0;
#pragma unroll
    for (int i = 0; i < 4; ++i) {
      const float4 v = *(const float4*)(src + i * 4);
      *(float4*)&Bs[IDX(r, k0 + i * 4)] = v;
    }
  }
  __syncthreads();

  const int tx = t & 15, ty = t >> 4;
  const int r0 = ty * 8, c0 = tx * 4;

  float4 acc[8][4];
#pragma unroll
  for (int rr = 0; rr < 8; ++rr)
#pragma unroll
    for (int cc = 0; cc < 4; ++cc) acc[rr][cc] = make_float4(0.f, 0.f, 0.f, 0.f);

  int aoff[8], boff[4];
#pragma unroll
  for (int rr = 0; rr < 8; ++rr) aoff[rr] = IDX(r0 + rr, 0);
#pragma unroll
  for (int cc = 0; cc < 4; ++cc) boff[cc] = IDX(c0 + cc, 0);

#pragma unroll 4
  for (int dg = 0; dg < 16; ++dg) {
    float4 av[8], bv[4];
#pragma unroll
    for (int rr = 0; rr < 8; ++rr) av[rr] = *(const float4*)&As[aoff[rr] + dg * 4];
#pragma unroll
    for (int cc = 0; cc < 4; ++cc) bv[cc] = *(const float4*)&Bs[boff[cc] + dg * 4];
#pragma unroll
    for (int rr = 0; rr < 8; ++rr)
#pragma unroll
      for (int cc = 0; cc < 4; ++cc) {
        acc[rr][cc].x += av[rr].x * bv[cc].x;
        acc[rr][cc].y += av[rr].y * bv[cc].y;
        acc[rr][cc].z += av[rr].z * bv[cc].z;
        acc[rr][cc].w += av[rr].w * bv[cc].w;
      }
  }

  // ---- epilogue: (x+y+z+w) * s_j, store ----
  const float4 sjv = *(const float4*)(srb + tj * 64 + c0);
  float* out = adj + (size_t)b * N_ * N_ + (size_t)(ti * 128 + r0) * N_ + tj * 64 + c0;
#pragma unroll
  for (int rr = 0; rr < 8; ++rr) {
    float4 o;
    o.x = (acc[rr][0].x + acc[rr][0].y + acc[rr][0].z + acc[rr][0].w) * sjv.x;
    o.y = (acc[rr][1].x + acc[rr][1].y + acc[rr][1].z + acc[rr][1].w) * sjv.y;
    o.z = (acc[rr][2].x + acc[rr][2].y + acc[rr][2].z + acc[rr][2].w) * sjv.z;
    o.w = (acc[rr][3].x + acc[rr][3].y + acc[rr][3].z + acc[rr][3].w) * sjv.w;
    *(float4*)(out + (size_t)rr * N_) = o;
  }
}

// ---------------------------------------------------------------------------
// Kernel C: in-place top-16 per row. (round-11 logic, passing.)
// NEW: block->row mapping REVERSED so topk reads rows newest-first (LIFO
// against sim's FIFO write order) -> L3 serves most reads before eviction.
// Selection logic and written bits unchanged.
// ---------------------------------------------------------------------------
__device__ __forceinline__ unsigned mono32(float v) {
  unsigned u = __float_as_uint(v);
  return u ^ ((unsigned)((int)u >> 31) | 0x80000000u);
}

__global__ __launch_bounds__(256) void topk_kernel(float* __restrict__ adj) {
  const int lane = threadIdx.x & 63;
  const int wid = threadIdx.x >> 6;
  const int rblk = (B_ * N_) / 4 - 1 - blockIdx.x;  // reversed block order
  const size_t row = (size_t)rblk * 4 + wid;        // 0..32767, newest first
  float* rp = adj + row * N_;

  // element j = (s>>2)*256 + lane*4 + (s&3) lives in vals[s]
  float vals[32];
#pragma unroll
  for (int g = 0; g < 8; ++g) {
    const float4 v = *((const float4*)rp + g * 64 + lane);
    vals[g * 4 + 0] = v.x; vals[g * 4 + 1] = v.y;
    vals[g * 4 + 2] = v.z; vals[g * 4 + 3] = v.w;
  }

  // ---- per-lane top-2 (ascending slot scan, strict > => lowest j on ties)
  float v1 = vals[0], v2 = -2.f;
  int s1 = 0, sB = 0;
#pragma unroll
  for (int s = 1; s < 32; ++s) {
    const float v = vals[s];
    if (v > v1) { v2 = v1; sB = s1; v1 = v; s1 = s; }
    else if (v > v2) { v2 = v; sB = s; }
  }
#define SLOT2J(S) ((((S) >> 2) << 8) + (lane << 2) + ((S)&3))
  unsigned long long lk =
      ((unsigned long long)mono32(v1) << 32) | (unsigned)(N_ - 1 - SLOT2J(s1));
  unsigned long long k2 =
      ((unsigned long long)mono32(v2) << 32) | (unsigned)(N_ - 1 - SLOT2J(sB));

  unsigned taken = 0u;
  int nlost = 0;

  for (int it = 0; it < K_; ++it) {
    const unsigned lv = (unsigned)(lk >> 32);
    unsigned bv = lv;
#pragma unroll
    for (int off = 32; off; off >>= 1) {
      const unsigned ov = __shfl_xor(bv, off, 64);
      if (ov > bv) bv = ov;
    }
    const unsigned long long mask = __ballot(lv == bv);
    unsigned long long bk;
    if (__popcll(mask) == 1) {
      const int srcl = (int)(__ffsll((long long)mask) - 1);
      bk = __shfl(lk, srcl, 64);
    } else {
      bk = lk;  // cross-lane value tie (rare, wave-uniform): exact u64
#pragma unroll
      for (int off = 32; off; off >>= 1) {
        const unsigned long long ok = __shfl_xor(bk, off, 64);
        if (ok > bk) bk = ok;
      }
    }

    const int j = N_ - 1 - (int)(bk & 0xFFFFFFFFull);
    const bool own = ((j >> 2) & 63) == lane;
    if (own) {
      taken |= 1u << (((j >> 8) << 2) | (j & 3));
      if (it < K_ - 1) {
        if (nlost == 0) {
          lk = k2;        // promote cached #2
          nlost = 1;
        } else {
          nlost = 2;      // mark: rescan below
        }
      }
    }
    if (own && nlost == 2) {
      float nv = -2.f; int ns = 0;
#pragma unroll
      for (int s = 0; s < 32; ++s) {
        if (!((taken >> s) & 1u) && vals[s] > nv) { nv = vals[s]; ns = s; }
      }
      lk = ((unsigned long long)mono32(nv) << 32) |
           (unsigned)(N_ - 1 - SLOT2J(ns));
    }
  }

  // merged write: winners keep value, everything else zero
#pragma unroll
  for (int g = 0; g < 8; ++g) {
    float4 o;
    o.x = ((taken >> (g * 4 + 0)) & 1u) ? vals[g * 4 + 0] : 0.f;
    o.y = ((taken >> (g * 4 + 1)) & 1u) ? vals[g * 4 + 1] : 0.f;
    o.z = ((taken >> (g * 4 + 2)) & 1u) ? vals[g * 4 + 2] : 0.f;
    o.w = ((taken >> (g * 4 + 3)) & 1u) ? vals[g * 4 + 3] : 0.f;
    *((float4*)rp + g * 64 + lane) = o;
  }
}

extern "C" void kernel_launch(void* const* d_in, const int* in_sizes, int n_in,
                              void* d_out, int out_size, void* d_ws, size_t ws_size,
                              hipStream_t stream) {
  const float* x  = (const float*)d_in[0];
  const float* W1 = (const float*)d_in[1];
  const float* b1 = (const float*)d_in[2];
  const float* W2 = (const float*)d_in[3];
  const float* b2 = (const float*)d_in[4];

  float* adj  = (float*)d_out;                              // B*N*N
  float* embo = (float*)d_out + (size_t)B_ * N_ * N_;       // B*N*H
  float* sref = (float*)d_ws;                               // B*N floats

  emb_kernel<<<(B_ * N_) / 4, 256, 0, stream>>>(x, W1, b1, W2, b2, embo, sref);
  sim_kernel<<<B_ * (N_ / 128) * (N_ / 64), 256, 0, stream>>>(embo, sref, adj);
  topk_kernel<<<(B_ * N_) / 4, 256, 0, stream>>>(adj);
}